// Round 22
// baseline (59.922 us; speedup 1.0000x reference)
//
#include <hip/hip_runtime.h>
#include <hip/hip_bf16.h>

// GMM log-likelihood, N=65536, K=32, F=128.
// R21 (triangular compaction + LDS-cached prep) + SOFTWARE-PIPELINED EPILOGUE:
// at iter k the wave does LSE(k-2) and squares(k-1) BEFORE MFMA(k) -- the
// VALU epilogue fills the 10-ds_read latency window instead of sitting after
// the MFMA drain. Needs 2 acc banks but their lifetimes are sequential
// (prev read by squares before cur is MFMA-written) -> peak ~205/256 regs.
// xch pipeline 2-deep: write(k-1) at iter k pre-barrier, read(k-2) at iter k
// top; phase = comp&1, reuse gap = 2 barriers (race-checked). Anti-phase
// sleep removed (R20: neutral).

#define NPTS 65536
#define KC 32
#define FD 128
#define SLABB 20480  // 20 chunks * 64 lanes * 16 B per component (triangular)

typedef __attribute__((ext_vector_type(8))) short short8;
typedef __attribute__((ext_vector_type(8))) unsigned short ushort8;
typedef __attribute__((ext_vector_type(16))) float f32x16;

#define MFMA(A, B, C) __builtin_amdgcn_mfma_f32_32x32x16_bf16((A), (B), (C), 0, 0, 0)

static __device__ __forceinline__ unsigned short f2bf(float f) {
  unsigned int u = __float_as_uint(f);
  u += 0x7FFFu + ((u >> 16) & 1u);  // RNE
  return (unsigned short)(u >> 16);
}

static __device__ __forceinline__ void gll(const unsigned char* g, unsigned char* l) {
  __builtin_amdgcn_global_load_lds((const __attribute__((address_space(1))) void*)g,
                                   (__attribute__((address_space(3))) void*)l, 16, 0, 0);
}

// --- prep_all (R21): one block per component k, P_k LDS-cached ---
__global__ __launch_bounds__(256) void prep_all(const float* __restrict__ means,
                                                const float* __restrict__ P,
                                                const float* __restrict__ w,
                                                unsigned char* __restrict__ Aimg,
                                                unsigned char* __restrict__ Ximg,
                                                float* __restrict__ ck3) {
  const int k = blockIdx.x;   // 0..31
  const int t = threadIdx.x;  // 0..255
  const float* Pk = P + k * FD * FD;
  __shared__ float Pl[FD * 129];
  __shared__ float smp[FD], r1[FD], r2[FD];
  for (int i = t; i < (FD * FD) / 4; i += 256) {
    const float4 v4 = *(const float4*)(Pk + i * 4);
    const int f = (i * 4) >> 7, c = (i * 4) & 127;
    float* d = Pl + f * 129 + c;
    d[0] = v4.x; d[1] = v4.y; d[2] = v4.z; d[3] = v4.w;
  }
  __syncthreads();
  if (t < FD) {
    float acc = 0.f;
    for (int f = 0; f < FD; ++f) acc = fmaf(means[k * FD + f], Pl[f * 129 + t], acc);
    smp[t] = acc;
    r1[t] = logf(Pl[t * 129 + t]);
    r2[t] = acc * acc;
  }
  __syncthreads();
  if (t < FD) {
    float a2 = 0.f;
    for (int j = 0; j < FD; ++j) a2 = fmaf(Pl[t * 129 + j], smp[j], a2);
    const int id = ((t >> 4) * 64) + k + 32 * ((t >> 3) & 1);
    *(unsigned short*)(Ximg + (size_t)id * 16 + (t & 7) * 2) = f2bf(a2);
  }
  for (int off = 64; off; off >>= 1) {
    if (t < off) { r1[t] += r1[t + off]; r2[t] += r2[t + off]; }
    __syncthreads();
  }
  if (t == 0)
    ck3[k] = logf(w[k]) + r1[0] - 0.5f * ((float)FD * 1.8378770664093453f + r2[0]);
  for (int i = t; i < 1280; i += 256) {
    const int c = i >> 6, l = i & 63;
    int q, s;
    if (c < 8)       { q = 0; s = c; }
    else if (c < 10) { q = 3; s = c - 2; }
    else if (c < 16) { q = 1; s = c - 8; }
    else             { q = 2; s = c - 12; }
    const int g = q * 32 + (l & 31);
    const int f0 = 16 * s + 8 * (l >> 5);
    ushort8 o;
#pragma unroll
    for (int j = 0; j < 8; ++j) o[j] = f2bf(Pl[(f0 + j) * 129 + g]);
    *(ushort8*)(Aimg + (size_t)k * SLABB + (size_t)i * 16) = o;
  }
}

// --- main ---
__global__ __launch_bounds__(256, 2) void gmm_main(const float* __restrict__ x,
                                                   const unsigned char* __restrict__ Aimg,
                                                   const unsigned char* __restrict__ Ximg,
                                                   const float* __restrict__ ck3,
                                                   float* __restrict__ out) {
  __shared__ __align__(16) unsigned char abuf[2 * SLABB];  // 40 KB
  __shared__ __align__(16) float xvt[4][KC][32];           // 16 KB, wave-private
  __shared__ __align__(16) float xch[2][4][32];
  __shared__ float ck[KC];
  const int tid = threadIdx.x;
  const int wid = tid >> 6;
  const int lane = tid & 63;
  const int half = lane >> 5;
  const int ln = lane & 31;
  const int p = wid & 1;    // g-tile pair: p=0 -> {0,3}, p=1 -> {1,2}
  const int nq = wid >> 1;  // n-half this wave owns (64 x-rows, tiles t=0,1)
  const int nbase = blockIdx.x * 128;

  if (tid < KC) ck[tid] = ck3[tid];

  // prologue staging: Ximg (8 KB) -> buf1, slab0 -> buf0 (5 gll/wave)
  {
    const unsigned char* gx = Ximg + wid * 2048 + lane * 16;
    unsigned char* lx = abuf + SLABB + wid * 2048;
    gll(gx, lx);
    gll(gx + 1024, lx + 1024);
    const unsigned char* gs = Aimg + wid * 5120 + lane * 16;
    unsigned char* ls = abuf + wid * 5120;
#pragma unroll
    for (int i = 0; i < 5; ++i) gll(gs + i * 1024, ls + i * 1024);
  }

  // B fragments: this wave's 64 x-rows (2 n-tiles), resident all kernel.
  short8 xf[2][8];
#pragma unroll
  for (int t = 0; t < 2; ++t) {
    const float* xr = x + (size_t)(nbase + nq * 64 + t * 32 + ln) * FD + 8 * half;
#pragma unroll
    for (int s = 0; s < 8; ++s) {
      const float4 a = *(const float4*)(xr + 16 * s);
      const float4 b = *(const float4*)(xr + 16 * s + 4);
      short8 f;
      f[0] = (short)f2bf(a.x); f[1] = (short)f2bf(a.y);
      f[2] = (short)f2bf(a.z); f[3] = (short)f2bf(a.w);
      f[4] = (short)f2bf(b.x); f[5] = (short)f2bf(b.y);
      f[6] = (short)f2bf(b.z); f[7] = (short)f2bf(b.w);
      xf[t][s] = f;
    }
  }

  f32x16 zc;  // persistent zero C-operand
#pragma unroll
  for (int i = 0; i < 16; ++i) zc[i] = 0.f;

  asm volatile("s_waitcnt vmcnt(0)" ::: "memory");
  __syncthreads();

  // xv mini-GEMM for the n-tile this wave finalizes (t == p) -> xvt table.
  {
    const unsigned char* xb = abuf + SLABB + lane * 16;
    f32x16 xv;
    {
      const short8 fx = *(const short8*)xb;
      xv = MFMA(fx, p ? xf[1][0] : xf[0][0], zc);
    }
#pragma unroll
    for (int s = 1; s < 8; ++s) {
      const short8 fx = *(const short8*)(xb + s * 1024);
      xv = MFMA(fx, p ? xf[1][s] : xf[0][s], xv);
    }
#pragma unroll
    for (int i = 0; i < 16; ++i) {
      const int kk = (i & 3) + 8 * (i >> 2) + 4 * half;
      xvt[wid][kk][ln] = xv[i];
    }
  }
  __syncthreads();  // Ximg consumed; buf1 free for slab1 staging

  float m = -__builtin_inff(), ssum = 0.f, sownC = 0.f;
  f32x16 accA[4], accB[4];

  // pipelined body: at iter k -- LSE(k-2), squares(k-1) from prev, MFMA(k)
  // into cur. VALU epilogue fills the ds_read latency window.
  auto body = [&](int k, f32x16 (&cur)[4], f32x16 (&prev)[4]) {
    const int RB = (k & 1) * SLABB;
    const int WB = SLABB - RB;
    const unsigned char* rb = abuf + RB + p * 10240 + lane * 16;
    short8 fr[10];
#pragma unroll
    for (int i = 0; i < 10; ++i) fr[i] = *(const short8*)(rb + i * 1024);
    if (k + 1 < KC) {  // stage slab k+1 (5 gll per wave)
      const unsigned char* gs = Aimg + (size_t)(k + 1) * SLABB + wid * 5120 + lane * 16;
      unsigned char* ls = abuf + WB + wid * 5120;
#pragma unroll
      for (int i = 0; i < 5; ++i) gll(gs + i * 1024, ls + i * 1024);
    }
    // LSE(k-2): xch published by barrier at end of iter k-1; phase (k-2)&1 = k&1
    if (k >= 2) {
      float sfull = sownC + xch[k & 1][wid][ln];
      sfull = fmaf(-2.f, xvt[wid][k - 2][ln], sfull);
      float vv = ck[k - 2] - 0.5f * sfull;
      float nm = fmaxf(m, vv);
      ssum = ssum * __expf(m - nm) + __expf(vv - nm);
      m = nm;
    }
    // squares(k-1) from prev bank (dies before cur is written)
    if (k >= 1) {
      float q0a = 0.f, q1a = 0.f, q0b = 0.f, q1b = 0.f;
#pragma unroll
      for (int i = 0; i < 16; ++i) {
        q0a = fmaf(prev[0][i], prev[0][i], q0a);
        q1a = fmaf(prev[1][i], prev[1][i], q1a);
        q0b = fmaf(prev[2][i], prev[2][i], q0b);
        q1b = fmaf(prev[3][i], prev[3][i], q1b);
      }
      float q0 = q0a + q0b, q1 = q1a + q1b;
      q0 += __shfl_xor(q0, 32, 64);
      q1 += __shfl_xor(q1, 32, 64);
      sownC = p ? q1 : q0;
      const float soth = p ? q0 : q1;
      if (half == 0) xch[(k & 1) ^ 1][wid ^ 1][ln] = soth;  // phase (k-1)&1
    }
    // MFMA(k) into cur
    __builtin_amdgcn_s_setprio(1);
    if (p == 0) {
      cur[0] = MFMA(fr[0], xf[0][0], zc);
      cur[1] = MFMA(fr[0], xf[1][0], zc);
#pragma unroll
      for (int s = 1; s < 8; ++s) {
        cur[0] = MFMA(fr[s], xf[0][s], cur[0]);
        cur[1] = MFMA(fr[s], xf[1][s], cur[1]);
      }
      cur[2] = MFMA(fr[8], xf[0][6], zc);
      cur[3] = MFMA(fr[8], xf[1][6], zc);
      cur[2] = MFMA(fr[9], xf[0][7], cur[2]);
      cur[3] = MFMA(fr[9], xf[1][7], cur[3]);
    } else {
      cur[0] = MFMA(fr[0], xf[0][2], zc);
      cur[1] = MFMA(fr[0], xf[1][2], zc);
#pragma unroll
      for (int s = 1; s < 6; ++s) {
        cur[0] = MFMA(fr[s], xf[0][s + 2], cur[0]);
        cur[1] = MFMA(fr[s], xf[1][s + 2], cur[1]);
      }
      cur[2] = MFMA(fr[6], xf[0][4], zc);
      cur[3] = MFMA(fr[6], xf[1][4], zc);
#pragma unroll
      for (int j = 1; j < 4; ++j) {
        cur[2] = MFMA(fr[6 + j], xf[0][4 + j], cur[2]);
        cur[3] = MFMA(fr[6 + j], xf[1][4 + j], cur[3]);
      }
    }
    __builtin_amdgcn_s_setprio(0);
    if (k + 1 < KC) asm volatile("s_waitcnt vmcnt(0)" ::: "memory");
    __syncthreads();  // publishes slab k+1 + xch(k-1)
  };

  for (int k2 = 0; k2 < KC; k2 += 2) {
    body(k2, accA, accB);
    body(k2 + 1, accB, accA);
  }

  // tail: LSE(30), squares(31)+xch, barrier, LSE(31)
  {
    float sfull = sownC + xch[0][wid][ln];  // phase 30&1 = 0
    sfull = fmaf(-2.f, xvt[wid][KC - 2][ln], sfull);
    float vv = ck[KC - 2] - 0.5f * sfull;
    float nm = fmaxf(m, vv);
    ssum = ssum * __expf(m - nm) + __expf(vv - nm);
    m = nm;
    float q0a = 0.f, q1a = 0.f, q0b = 0.f, q1b = 0.f;
#pragma unroll
    for (int i = 0; i < 16; ++i) {
      q0a = fmaf(accB[0][i], accB[0][i], q0a);
      q1a = fmaf(accB[1][i], accB[1][i], q1a);
      q0b = fmaf(accB[2][i], accB[2][i], q0b);
      q1b = fmaf(accB[3][i], accB[3][i], q1b);
    }
    float q0 = q0a + q0b, q1 = q1a + q1b;
    q0 += __shfl_xor(q0, 32, 64);
    q1 += __shfl_xor(q1, 32, 64);
    float sown = p ? q1 : q0;
    const float soth = p ? q0 : q1;
    if (half == 0) xch[1][wid ^ 1][ln] = soth;  // phase 31&1 = 1
    __syncthreads();
    float sf2 = sown + xch[1][wid][ln];
    sf2 = fmaf(-2.f, xvt[wid][KC - 1][ln], sf2);
    float v2 = ck[KC - 1] - 0.5f * sf2;
    float nm2 = fmaxf(m, v2);
    ssum = ssum * __expf(m - nm2) + __expf(v2 - nm2);
    m = nm2;
  }

  if (half == 0) out[nbase + nq * 64 + p * 32 + ln] = m + logf(ssum);
}

extern "C" void kernel_launch(void* const* d_in, const int* in_sizes, int n_in,
                              void* d_out, int out_size, void* d_ws, size_t ws_size,
                              hipStream_t stream) {
  const float* x = (const float*)d_in[0];
  const float* means = (const float*)d_in[1];
  const float* P = (const float*)d_in[2];
  const float* w = (const float*)d_in[3];
  float* out = (float*)d_out;

  unsigned char* ws = (unsigned char*)d_ws;
  unsigned char* Aimg = ws;                      // 32 * 20480 = 655360 B
  unsigned char* Ximg = ws + 655360;             // 8192 B
  float* ck3 = (float*)(ws + 655360 + 8192);     // 128 B

  prep_all<<<32, 256, 0, stream>>>(means, P, w, Aimg, Ximg, ck3);
  gmm_main<<<NPTS / 128, 256, 0, stream>>>(x, Aimg, Ximg, ck3, out);
}

// Round 23
// 57.774 us; speedup vs baseline: 1.0372x; 1.0372x over previous
//
#include <hip/hip_runtime.h>
#include <hip/hip_bf16.h>

// GMM log-likelihood, N=65536, K=32, F=128.
// BEST-KNOWN BUILD (R21) minus the anti-phase sleep (measured neutral, costs
// ~0.75us idle on half the blocks).
// Main: triangular compaction (lower-tri P => frag chunk (q,s) nonzero only
// for s >= 2q -> 20 of 32 chunks/comp). Wave (p,nq): p=0 owns g-tiles {0,3}
// (8+2 frags), p=1 owns {1,2} (6+4); 10 frags -> 20 MFMAs/comp; pairwise xch
// combine with partner wid^1; v-trick mean fold (xv in wave-private xvt LDS
// table); zc C-operand; 1 barrier/comp. 2 blocks/CU, ~172/256 unified regs.
// Prep: single fused kernel, P_k LDS-cached (129-float padded rows).

#define NPTS 65536
#define KC 32
#define FD 128
#define SLABB 20480  // 20 chunks * 64 lanes * 16 B per component (triangular)

typedef __attribute__((ext_vector_type(8))) short short8;
typedef __attribute__((ext_vector_type(8))) unsigned short ushort8;
typedef __attribute__((ext_vector_type(16))) float f32x16;

#define MFMA(A, B, C) __builtin_amdgcn_mfma_f32_32x32x16_bf16((A), (B), (C), 0, 0, 0)

static __device__ __forceinline__ unsigned short f2bf(float f) {
  unsigned int u = __float_as_uint(f);
  u += 0x7FFFu + ((u >> 16) & 1u);  // RNE
  return (unsigned short)(u >> 16);
}

static __device__ __forceinline__ void gll(const unsigned char* g, unsigned char* l) {
  __builtin_amdgcn_global_load_lds((const __attribute__((address_space(1))) void*)g,
                                   (__attribute__((address_space(3))) void*)l, 16, 0, 0);
}

// --- prep_all: one block per component k (256 threads), P_k LDS-cached ---
__global__ __launch_bounds__(256) void prep_all(const float* __restrict__ means,
                                                const float* __restrict__ P,
                                                const float* __restrict__ w,
                                                unsigned char* __restrict__ Aimg,
                                                unsigned char* __restrict__ Ximg,
                                                float* __restrict__ ck3) {
  const int k = blockIdx.x;   // 0..31
  const int t = threadIdx.x;  // 0..255
  const float* Pk = P + k * FD * FD;
  __shared__ float Pl[FD * 129];  // row f at Pl + f*129 (pad kills bank conflicts)
  __shared__ float smp[FD], r1[FD], r2[FD];
  // cooperative coalesced load: 4096 float4s, 16 per thread
  for (int i = t; i < (FD * FD) / 4; i += 256) {
    const float4 v4 = *(const float4*)(Pk + i * 4);
    const int f = (i * 4) >> 7, c = (i * 4) & 127;
    float* d = Pl + f * 129 + c;
    d[0] = v4.x; d[1] = v4.y; d[2] = v4.z; d[3] = v4.w;
  }
  __syncthreads();
  if (t < FD) {
    float acc = 0.f;
    for (int f = 0; f < FD; ++f) acc = fmaf(means[k * FD + f], Pl[f * 129 + t], acc);
    smp[t] = acc;
    r1[t] = logf(Pl[t * 129 + t]);
    r2[t] = acc * acc;
  }
  __syncthreads();
  if (t < FD) {
    float a2 = 0.f;
    for (int j = 0; j < FD; ++j) a2 = fmaf(Pl[t * 129 + j], smp[j], a2);
    // Ximg frag-major position for (row k, col t)
    const int id = ((t >> 4) * 64) + k + 32 * ((t >> 3) & 1);
    *(unsigned short*)(Ximg + (size_t)id * 16 + (t & 7) * 2) = f2bf(a2);
  }
  for (int off = 64; off; off >>= 1) {
    if (t < off) { r1[t] += r1[t + off]; r2[t] += r2[t + off]; }
    __syncthreads();
  }
  if (t == 0)
    ck3[k] = logf(w[k]) + r1[0] - 0.5f * ((float)FD * 1.8378770664093453f + r2[0]);
  // triangular A image: 20 chunks c x 64 lanes l = 1280 stores, 5 per thread.
  for (int i = t; i < 1280; i += 256) {
    const int c = i >> 6, l = i & 63;
    int q, s;
    if (c < 8)       { q = 0; s = c; }
    else if (c < 10) { q = 3; s = c - 2; }
    else if (c < 16) { q = 1; s = c - 8; }
    else             { q = 2; s = c - 12; }
    const int g = q * 32 + (l & 31);
    const int f0 = 16 * s + 8 * (l >> 5);
    ushort8 o;
#pragma unroll
    for (int j = 0; j < 8; ++j) o[j] = f2bf(Pl[(f0 + j) * 129 + g]);
    *(ushort8*)(Aimg + (size_t)k * SLABB + (size_t)i * 16) = o;
  }
}

// --- main ---
__global__ __launch_bounds__(256, 2) void gmm_main(const float* __restrict__ x,
                                                   const unsigned char* __restrict__ Aimg,
                                                   const unsigned char* __restrict__ Ximg,
                                                   const float* __restrict__ ck3,
                                                   float* __restrict__ out) {
  __shared__ __align__(16) unsigned char abuf[2 * SLABB];  // 40 KB
  __shared__ __align__(16) float xvt[4][KC][32];           // 16 KB, wave-private
  __shared__ __align__(16) float xch[2][4][32];
  __shared__ float ck[KC];
  const int tid = threadIdx.x;
  const int wid = tid >> 6;
  const int lane = tid & 63;
  const int half = lane >> 5;
  const int ln = lane & 31;
  const int p = wid & 1;    // g-tile pair: p=0 -> {0,3}, p=1 -> {1,2}
  const int nq = wid >> 1;  // n-half this wave owns (64 x-rows, tiles t=0,1)
  const int nbase = blockIdx.x * 128;

  if (tid < KC) ck[tid] = ck3[tid];

  // prologue staging: Ximg (8 KB) -> buf1, slab0 -> buf0 (5 gll/wave)
  {
    const unsigned char* gx = Ximg + wid * 2048 + lane * 16;
    unsigned char* lx = abuf + SLABB + wid * 2048;
    gll(gx, lx);
    gll(gx + 1024, lx + 1024);
    const unsigned char* gs = Aimg + wid * 5120 + lane * 16;
    unsigned char* ls = abuf + wid * 5120;
#pragma unroll
    for (int i = 0; i < 5; ++i) gll(gs + i * 1024, ls + i * 1024);
  }

  // B fragments: this wave's 64 x-rows (2 n-tiles), resident all kernel.
  short8 xf[2][8];
#pragma unroll
  for (int t = 0; t < 2; ++t) {
    const float* xr = x + (size_t)(nbase + nq * 64 + t * 32 + ln) * FD + 8 * half;
#pragma unroll
    for (int s = 0; s < 8; ++s) {
      const float4 a = *(const float4*)(xr + 16 * s);
      const float4 b = *(const float4*)(xr + 16 * s + 4);
      short8 f;
      f[0] = (short)f2bf(a.x); f[1] = (short)f2bf(a.y);
      f[2] = (short)f2bf(a.z); f[3] = (short)f2bf(a.w);
      f[4] = (short)f2bf(b.x); f[5] = (short)f2bf(b.y);
      f[6] = (short)f2bf(b.z); f[7] = (short)f2bf(b.w);
      xf[t][s] = f;
    }
  }

  f32x16 zc;  // persistent zero C-operand
#pragma unroll
  for (int i = 0; i < 16; ++i) zc[i] = 0.f;

  asm volatile("s_waitcnt vmcnt(0)" ::: "memory");
  __syncthreads();

  // xv mini-GEMM for the n-tile this wave finalizes (t == p) -> xvt table.
  // (ternary register-select, never xf[p][s] -- rule-20)
  {
    const unsigned char* xb = abuf + SLABB + lane * 16;
    f32x16 xv;
    {
      const short8 fx = *(const short8*)xb;
      xv = MFMA(fx, p ? xf[1][0] : xf[0][0], zc);
    }
#pragma unroll
    for (int s = 1; s < 8; ++s) {
      const short8 fx = *(const short8*)(xb + s * 1024);
      xv = MFMA(fx, p ? xf[1][s] : xf[0][s], xv);
    }
#pragma unroll
    for (int i = 0; i < 16; ++i) {
      const int kk = (i & 3) + 8 * (i >> 2) + 4 * half;
      xvt[wid][kk][ln] = xv[i];
    }
  }
  __syncthreads();  // Ximg consumed; buf1 free for slab1 staging

  float m = -__builtin_inff(), ssum = 0.f;

  for (int k = 0; k < KC; ++k) {
    const int RB = (k & 1) * SLABB;
    const int WB = SLABB - RB;
    const int ph = k & 1;
    // this wave's 10 triangular frags (consecutive chunks, conflict-free)
    const unsigned char* rb = abuf + RB + p * 10240 + lane * 16;
    short8 fr[10];
#pragma unroll
    for (int i = 0; i < 10; ++i) fr[i] = *(const short8*)(rb + i * 1024);
    if (k + 1 < KC) {  // stage slab k+1 (5 gll per wave)
      const unsigned char* gs = Aimg + (size_t)(k + 1) * SLABB + wid * 5120 + lane * 16;
      unsigned char* ls = abuf + WB + wid * 5120;
#pragma unroll
      for (int i = 0; i < 5; ++i) gll(gs + i * 1024, ls + i * 1024);
    }
    f32x16 a00, a01, a10, a11;
    __builtin_amdgcn_s_setprio(1);
    if (p == 0) {
      // g-tile 0: full K (s=0..7); g-tile 3: s=6,7
      a00 = MFMA(fr[0], xf[0][0], zc);
      a01 = MFMA(fr[0], xf[1][0], zc);
#pragma unroll
      for (int s = 1; s < 8; ++s) {
        a00 = MFMA(fr[s], xf[0][s], a00);
        a01 = MFMA(fr[s], xf[1][s], a01);
      }
      a10 = MFMA(fr[8], xf[0][6], zc);
      a11 = MFMA(fr[8], xf[1][6], zc);
      a10 = MFMA(fr[9], xf[0][7], a10);
      a11 = MFMA(fr[9], xf[1][7], a11);
    } else {
      // g-tile 1: s=2..7; g-tile 2: s=4..7
      a00 = MFMA(fr[0], xf[0][2], zc);
      a01 = MFMA(fr[0], xf[1][2], zc);
#pragma unroll
      for (int s = 1; s < 6; ++s) {
        a00 = MFMA(fr[s], xf[0][s + 2], a00);
        a01 = MFMA(fr[s], xf[1][s + 2], a01);
      }
      a10 = MFMA(fr[6], xf[0][4], zc);
      a11 = MFMA(fr[6], xf[1][4], zc);
#pragma unroll
      for (int j = 1; j < 4; ++j) {
        a10 = MFMA(fr[6 + j], xf[0][4 + j], a10);
        a11 = MFMA(fr[6 + j], xf[1][4 + j], a11);
      }
    }
    __builtin_amdgcn_s_setprio(0);
    // epilogue: group-1 squares first (issue while group-2 MFMAs drain)
    float q0a = 0.f, q1a = 0.f;
#pragma unroll
    for (int i = 0; i < 16; ++i) {
      q0a = fmaf(a00[i], a00[i], q0a);
      q1a = fmaf(a01[i], a01[i], q1a);
    }
    float q0b = 0.f, q1b = 0.f;
#pragma unroll
    for (int i = 0; i < 16; ++i) {
      q0b = fmaf(a10[i], a10[i], q0b);
      q1b = fmaf(a11[i], a11[i], q1b);
    }
    float q0 = q0a + q0b, q1 = q1a + q1b;
    q0 += __shfl_xor(q0, 32, 64);  // both halves hold the 64-g pair partials
    q1 += __shfl_xor(q1, 32, 64);
    float sown = p ? q1 : q0;  // n-tile this wave finalizes (t == p)
    float soth = p ? q0 : q1;  // n-tile the partner (wid^1) finalizes
    if (half == 0) xch[ph][wid ^ 1][ln] = soth;
    if (k + 1 < KC) asm volatile("s_waitcnt vmcnt(0)" ::: "memory");
    __syncthreads();  // xch visibility + staging handoff (one barrier/comp)
    float sfull = sown + xch[ph][wid][ln];  // + partner's 64 g -> full 128-g
    sfull = fmaf(-2.f, xvt[wid][k][ln], sfull);  // v-trick correction
    float vv = ck[k] - 0.5f * sfull;
    float nm = fmaxf(m, vv);
    ssum = ssum * __expf(m - nm) + __expf(vv - nm);
    m = nm;
  }

  if (half == 0) out[nbase + nq * 64 + p * 32 + ln] = m + logf(ssum);
}

extern "C" void kernel_launch(void* const* d_in, const int* in_sizes, int n_in,
                              void* d_out, int out_size, void* d_ws, size_t ws_size,
                              hipStream_t stream) {
  const float* x = (const float*)d_in[0];
  const float* means = (const float*)d_in[1];
  const float* P = (const float*)d_in[2];
  const float* w = (const float*)d_in[3];
  float* out = (float*)d_out;

  unsigned char* ws = (unsigned char*)d_ws;
  unsigned char* Aimg = ws;                      // 32 * 20480 = 655360 B
  unsigned char* Ximg = ws + 655360;             // 8192 B
  float* ck3 = (float*)(ws + 655360 + 8192);     // 128 B

  prep_all<<<32, 256, 0, stream>>>(means, P, w, Aimg, Ximg, ck3);
  gmm_main<<<NPTS / 128, 256, 0, stream>>>(x, Aimg, Ximg, ck3, out);
}